// Round 16
// baseline (2664.191 us; speedup 1.0000x reference)
//
#include <hip/hip_runtime.h>
#include <hip/hip_fp16.h>

#define NN 1024
#define NST 16

typedef _Float16 v2h __attribute__((ext_vector_type(2)));
typedef _Float16 f16x8 __attribute__((ext_vector_type(8)));
typedef float f32x4 __attribute__((ext_vector_type(4)));
typedef unsigned int uint;
typedef unsigned long long u64;
typedef unsigned int u32x4 __attribute__((ext_vector_type(4)));

// Static device scratch.
__device__ __half g_W[NST][NN][2048];      // per stage row: [Wih_eff(1024) | Whh(1024)] fp16
__device__ float g_bias[NST][NN];          // combined bias fp32
__device__ u64 g_S[NST][NN][512];          // slot q = {1<<32 | fp16 h[2q+1],h[2q]}
__device__ float g_Hout[8][NN * NN];       // h of odd stages (pre-linear), fp32
__device__ _Float16 g_Wih16F[7][NN * NN];  // f16 Wih of folded stages (st=2t, t=1..7)
__device__ _Float16 g_linW16[8][NN * NN];  // f16 linW

__device__ __forceinline__ v2h as_v2h(uint u) {
  union { uint u; v2h h; } c; c.u = u; return c.h;
}
__device__ __forceinline__ uint pk2(float a, float b) {
  union { v2h h; uint u; } c; c.h.x = (_Float16)a; c.h.y = (_Float16)b; return c.u;
}
// 16B-unit swizzle: low3' = (u + (u>>3)) & 7 (R12-proven pattern).
__device__ __forceinline__ int swzu(int u) {
  return (u & ~7) | ((u + (u >> 3)) & 7);
}
// Opaque (non-rematerializable) 16B load.
__device__ __forceinline__ u32x4 ld_opaque16(const __half* p) {
  u32x4 r;
  asm volatile("global_load_dwordx4 %0, %1, off" : "=v"(r) : "v"(p));
  return r;
}
__device__ __forceinline__ float fdot4(u32x4 w, u32x4 v, float a) {
  a = __builtin_amdgcn_fdot2(as_v2h(w.x), as_v2h(v.x), a, false);
  a = __builtin_amdgcn_fdot2(as_v2h(w.y), as_v2h(v.y), a, false);
  a = __builtin_amdgcn_fdot2(as_v2h(w.z), as_v2h(v.z), a, false);
  a = __builtin_amdgcn_fdot2(as_v2h(w.w), as_v2h(v.w), a, false);
  return a;
}
// 32-lane-group sum via DPP (4x row_shr + row_bcast15), pure VALU.
// Result: lane31 = sum(lanes 0..31), lane63 = sum(lanes 32..63).
__device__ __forceinline__ float dpp_reduce32(float v) {
  int t;
  t = __builtin_amdgcn_update_dpp(0, __float_as_int(v), 0x111, 0xF, 0xF, true); v += __int_as_float(t);
  t = __builtin_amdgcn_update_dpp(0, __float_as_int(v), 0x112, 0xF, 0xF, true); v += __int_as_float(t);
  t = __builtin_amdgcn_update_dpp(0, __float_as_int(v), 0x114, 0xF, 0xF, true); v += __int_as_float(t);
  t = __builtin_amdgcn_update_dpp(0, __float_as_int(v), 0x118, 0xF, 0xF, true); v += __int_as_float(t);
  t = __builtin_amdgcn_update_dpp(0, __float_as_int(v), 0x142, 0xF, 0xF, true); v += __int_as_float(t);
  return v;
}

// ---- zero exchange slots (every launch, replay determinism) ----
__global__ void k_init() {
  const size_t n = (size_t)NST * NN * 512;
  size_t i = (size_t)blockIdx.x * blockDim.x + threadIdx.x;
  const size_t stride = (size_t)gridDim.x * blockDim.x;
  u64* p = &g_S[0][0][0];
  for (; i < n; i += stride) p[i] = 0ull;
}

// ---- pack to fp16: g_W (Whh all, Wih non-folded), g_Wih16F (folded), g_linW16 ----
__global__ void k_pack(const float* __restrict__ Wih, const float* __restrict__ Whh,
                       const float* __restrict__ linW) {
  const size_t total = (size_t)NST * NN * NN;
  const size_t stride = (size_t)gridDim.x * blockDim.x;
  for (size_t i = (size_t)blockIdx.x * blockDim.x + threadIdx.x; i < total; i += stride) {
    const int st = (int)(i >> 20);
    const int m = (int)(i >> 10) & 1023;
    const int k = (int)i & 1023;
    g_W[st][m][1024 + k] = __float2half(Whh[i]);
    const int t = st >> 1, l = st & 1;
    if (l == 1 || t == 0) g_W[st][m][k] = __float2half(Wih[i]);
    else g_Wih16F[t - 1][(size_t)m * NN + k] = (_Float16)Wih[i];
  }
  const size_t ltotal = (size_t)8 * NN * NN;
  _Float16* lw = &g_linW16[0][0];
  for (size_t i = (size_t)blockIdx.x * blockDim.x + threadIdx.x; i < ltotal; i += stride)
    lw[i] = (_Float16)linW[i];
}

#define GPAD 40   // LDS f16 row stride for 32-wide K tiles

// ---- MFMA fold: W'(st=2t) = Wih16F[t-1] @ linW16[t-1], f32 accum -> f16 into g_W ----
__global__ __launch_bounds__(256) void k_fold(int dummy) {
  const int tm1 = blockIdx.z;
  const int st = (tm1 + 1) * 2;
  const _Float16* A = &g_Wih16F[tm1][0];
  const _Float16* B = &g_linW16[tm1][0];
  __shared__ _Float16 sA[128 * GPAD];
  __shared__ _Float16 sB[128 * GPAD];
  const int tid = threadIdx.x;
  const int bm = blockIdx.y << 7, bn = blockIdx.x << 7;
  const int lane = tid & 63, wid = tid >> 6;
  const int wm = wid >> 1, wn = wid & 1;
  const int lr = lane & 15, kc = (lane >> 4) << 3;
  f32x4 acc[4][4] = {};
  const int arow = tid >> 1, ahalf = tid & 1;           // A/B row staging
  const int bj = tid >> 3, bcs = tid & 7;               // B transpose staging

  for (int k0 = 0; k0 < NN; k0 += 32) {
    __syncthreads();
    {
      const u32x4 a0 = *(const u32x4*)&A[(size_t)(bm + arow) * NN + k0 + 16 * ahalf];
      const u32x4 a1 = *(const u32x4*)&A[(size_t)(bm + arow) * NN + k0 + 16 * ahalf + 8];
      u32x4* dst = (u32x4*)&sA[arow * GPAD + 16 * ahalf];
      dst[0] = a0; dst[1] = a1;
      union { u32x4 v; _Float16 h[8]; } ua, ub;
      ua.v = *(const u32x4*)&B[(size_t)(k0 + bj) * NN + bn + 16 * bcs];
      ub.v = *(const u32x4*)&B[(size_t)(k0 + bj) * NN + bn + 16 * bcs + 8];
      #pragma unroll
      for (int q = 0; q < 8; ++q) sB[(16 * bcs + q) * GPAD + bj] = ua.h[q];
      #pragma unroll
      for (int q = 0; q < 8; ++q) sB[(16 * bcs + 8 + q) * GPAD + bj] = ub.h[q];
    }
    __syncthreads();
    f16x8 af[4], bf[4];
    #pragma unroll
    for (int f = 0; f < 4; ++f) {
      af[f] = *(const f16x8*)&sA[(wm * 64 + f * 16 + lr) * GPAD + kc];
      bf[f] = *(const f16x8*)&sB[(wn * 64 + f * 16 + lr) * GPAD + kc];
    }
    #pragma unroll
    for (int fm = 0; fm < 4; ++fm)
      #pragma unroll
      for (int fn = 0; fn < 4; ++fn)
        acc[fm][fn] = __builtin_amdgcn_mfma_f32_16x16x32_f16(af[fm], bf[fn], acc[fm][fn], 0, 0, 0);
  }
  const int orow = (lane >> 4) << 2, ocol = lane & 15;
  #pragma unroll
  for (int fm = 0; fm < 4; ++fm)
    #pragma unroll
    for (int fn = 0; fn < 4; ++fn) {
      const int gr = bm + wm * 64 + fm * 16 + orow;
      const int gc = bn + wn * 64 + fn * 16 + ocol;
      #pragma unroll
      for (int r = 0; r < 4; ++r)
        g_W[st][gr + r][gc] = __float2half(acc[fm][fn][r]);
    }
}

// ---- MFMA epilogue: out[s][t][n] = Hout[t][s] @ linW16[t]^T + linb[t] ----
__global__ __launch_bounds__(256) void k_out(const float* __restrict__ linb,
                                             float* __restrict__ out) {
  const int t = blockIdx.z;
  const float* A = &g_Hout[t][0];
  const _Float16* B = &g_linW16[t][0];
  __shared__ _Float16 sA[128 * GPAD];
  __shared__ _Float16 sB[128 * GPAD];
  const int tid = threadIdx.x;
  const int bm = blockIdx.y << 7, bn = blockIdx.x << 7;
  const int lane = tid & 63, wid = tid >> 6;
  const int wm = wid >> 1, wn = wid & 1;
  const int lr = lane & 15, kc = (lane >> 4) << 3;
  f32x4 acc[4][4] = {};
  const int arow = tid >> 1, ahalf = tid & 1;

  for (int k0 = 0; k0 < NN; k0 += 32) {
    __syncthreads();
    {
      const float* srcA = &A[(size_t)(bm + arow) * NN + k0 + 16 * ahalf];
      const float4 f0 = *(const float4*)&srcA[0];
      const float4 f1 = *(const float4*)&srcA[4];
      const float4 f2 = *(const float4*)&srcA[8];
      const float4 f3 = *(const float4*)&srcA[12];
      u32x4 o0, o1;
      o0.x = pk2(f0.x, f0.y); o0.y = pk2(f0.z, f0.w);
      o0.z = pk2(f1.x, f1.y); o0.w = pk2(f1.z, f1.w);
      o1.x = pk2(f2.x, f2.y); o1.y = pk2(f2.z, f2.w);
      o1.z = pk2(f3.x, f3.y); o1.w = pk2(f3.z, f3.w);
      u32x4* dstA = (u32x4*)&sA[arow * GPAD + 16 * ahalf];
      dstA[0] = o0; dstA[1] = o1;
      const u32x4 b0 = *(const u32x4*)&B[(size_t)(bn + arow) * NN + k0 + 16 * ahalf];
      const u32x4 b1 = *(const u32x4*)&B[(size_t)(bn + arow) * NN + k0 + 16 * ahalf + 8];
      u32x4* dstB = (u32x4*)&sB[arow * GPAD + 16 * ahalf];
      dstB[0] = b0; dstB[1] = b1;
    }
    __syncthreads();
    f16x8 af[4], bf[4];
    #pragma unroll
    for (int f = 0; f < 4; ++f) {
      af[f] = *(const f16x8*)&sA[(wm * 64 + f * 16 + lr) * GPAD + kc];
      bf[f] = *(const f16x8*)&sB[(wn * 64 + f * 16 + lr) * GPAD + kc];
    }
    #pragma unroll
    for (int fm = 0; fm < 4; ++fm)
      #pragma unroll
      for (int fn = 0; fn < 4; ++fn)
        acc[fm][fn] = __builtin_amdgcn_mfma_f32_16x16x32_f16(af[fm], bf[fn], acc[fm][fn], 0, 0, 0);
  }
  const int orow = (lane >> 4) << 2, ocol = lane & 15;
  #pragma unroll
  for (int fm = 0; fm < 4; ++fm)
    #pragma unroll
    for (int fn = 0; fn < 4; ++fn) {
      const int gr = bm + wm * 64 + fm * 16 + orow;
      const int gc = bn + wn * 64 + fn * 16 + ocol;
      const float lb = linb[(size_t)t * NN + gc];
      #pragma unroll
      for (int r = 0; r < 4; ++r)
        out[(size_t)(gr + r) * 8192 + (size_t)t * NN + gc] = acc[fm][fn][r] + lb;
    }
}

// ---- combined bias per stage (64 WGs) ----
__global__ __launch_bounds__(256) void k_bias(const float* __restrict__ Wih,
    const float* __restrict__ bih, const float* __restrict__ bhh,
    const float* __restrict__ linb) {
  const int st = blockIdx.x, t = st >> 1, l = st & 1;
  const int tid = threadIdx.x;
  const int m = (blockIdx.y << 8) + tid;
  __shared__ float slb[NN];
  const bool folded = (l == 0 && t > 0);
  if (folded)
    for (int k = tid; k < NN; k += 256) slb[k] = linb[(size_t)(t - 1) * NN + k];
  __syncthreads();
  float b = bih[(size_t)st * NN + m] + bhh[(size_t)st * NN + m];
  if (folded) {
    const float* wr = Wih + (size_t)st * NN * NN + (size_t)m * NN;
    float s0 = 0, s1 = 0, s2 = 0, s3 = 0;
    for (int k = 0; k < NN; k += 4) {
      const float4 w = *(const float4*)&wr[k];
      s0 += w.x * slb[k]; s1 += w.y * slb[k + 1];
      s2 += w.z * slb[k + 2]; s3 += w.w * slb[k + 3];
    }
    b += (s0 + s1) + (s2 + s3);
  }
  g_bias[st][m] = b;
}

// ---- pipelined 16-stage scan: R=4 rows/thread (halves LDS reads vs R14) ----
// 256 WGs x 512 thr, 1 WG/CU, XCD-pinned stages. Thread (i=tid>>5, c=tid&31):
// rows woff+4i..+3, cols [32c,32c+32) of X AND H -> 8 b128 reads/tick (was 16).
// Split-phase tick; 5-op DPP reduce; lanes 31/63 (c==31) publish 2 slots each.
__global__ __launch_bounds__(512)
__attribute__((amdgpu_waves_per_eu(2, 2)))
void k_phase(const float* __restrict__ x) {
  __shared__ __align__(16) unsigned char comb[2][4096];  // units 0..127 X | 128..255 H (swz'd)
  const int tid = threadIdx.x;
  const int bid = blockIdx.x;
  const int st = ((bid & 7) << 1) + (bid >> 7);
  const int wg = (bid >> 3) & 15;
  const int woff = wg << 6;
  const int i = tid >> 5;      // row-quad 0..15
  const int c = tid & 31;      // col chunk 0..31
  const int row0 = woff + 4 * i;

#define LDX(RR, JJ) ld_opaque16(&g_W[st][row0 + (RR)][32 * c + 8 * (JJ)])
#define LDH(RR, JJ) ld_opaque16(&g_W[st][row0 + (RR)][1024 + 32 * c + 8 * (JJ)])
  u32x4 a00 = LDX(0,0), a01 = LDX(0,1), a02 = LDX(0,2), a03 = LDX(0,3);
  u32x4 a10 = LDX(1,0), a11 = LDX(1,1), a12 = LDX(1,2), a13 = LDX(1,3);
  u32x4 a20 = LDX(2,0), a21 = LDX(2,1), a22 = LDX(2,2), a23 = LDX(2,3);
  u32x4 a30 = LDX(3,0), a31 = LDX(3,1), a32 = LDX(3,2), a33 = LDX(3,3);
  u32x4 b00 = LDH(0,0), b01 = LDH(0,1), b02 = LDH(0,2), b03 = LDH(0,3);
  u32x4 b10 = LDH(1,0), b11 = LDH(1,1), b12 = LDH(1,2), b13 = LDH(1,3);
  u32x4 b20 = LDH(2,0), b21 = LDH(2,1), b22 = LDH(2,2), b23 = LDH(2,3);
  u32x4 b30 = LDH(3,0), b31 = LDH(3,1), b32 = LDH(3,2), b33 = LDH(3,3);
#undef LDX
#undef LDH
  asm volatile("s_waitcnt vmcnt(0)" ::: "memory");
  __builtin_amdgcn_sched_barrier(0);

  const float4 ba = *(const float4*)&g_bias[st][row0];

  // Loop-invariant comb byte offsets (write: unit tid>>2, dword tid&3; swizzled).
  const int uW = tid >> 2, off4 = (tid & 3) << 2;
  const int wbx = swzu(uW) * 16 + off4;
  const int wbh = swzu(128 + uW) * 16 + off4;
  // Loop-invariant read offsets: units 4c+JJ (X), 128+4c+JJ (H).
  const int rx0 = swzu(4 * c + 0) * 16, rx1 = swzu(4 * c + 1) * 16;
  const int rx2 = swzu(4 * c + 2) * 16, rx3 = swzu(4 * c + 3) * 16;
  const int rh0 = swzu(128 + 4 * c + 0) * 16, rh1 = swzu(128 + 4 * c + 1) * 16;
  const int rh2 = swzu(128 + 4 * c + 2) * 16, rh3 = swzu(128 + 4 * c + 3) * 16;
  const int slot0 = (woff >> 1) + 2 * i;   // publisher: c==31 (DPP result lanes 31/63)
  const bool isPub = (c == 31);

  for (int s = 0; s < NN; ++s) {
    unsigned char* cb = comb[s & 1];
    // ---------- phase A: upstream (slack-absorbed; sleep-poll) ----------
    uint xu = 0;
    if (st == 0) {
      const float2 xv = *(const float2*)&x[(size_t)s * 8192 + 2 * tid];
      xu = pk2(xv.x, xv.y);
    } else {
      const u64* pu = &g_S[st - 1][s][tid];
      for (;;) {
        const u64 a = __hip_atomic_load(pu, __ATOMIC_RELAXED, __HIP_MEMORY_SCOPE_AGENT);
        if (a >> 32) { xu = (uint)a; break; }
        __builtin_amdgcn_s_sleep(1);
      }
    }
    *(uint*)&cb[wbx] = xu;
    __syncthreads();   // bar1: X half ready

    // ---------- X-dot: 4 rows x 32 X-cols (own-h RT hides here) ----------
    float p0, p1, p2, p3;
    {
      const u32x4 v0 = *(const u32x4*)&cb[rx0];
      const u32x4 v1 = *(const u32x4*)&cb[rx1];
      const u32x4 v2 = *(const u32x4*)&cb[rx2];
      const u32x4 v3 = *(const u32x4*)&cb[rx3];
      p0 = fdot4(a03, v3, fdot4(a02, v2, fdot4(a01, v1, fdot4(a00, v0, 0.f))));
      p1 = fdot4(a13, v3, fdot4(a12, v2, fdot4(a11, v1, fdot4(a10, v0, 0.f))));
      p2 = fdot4(a23, v3, fdot4(a22, v2, fdot4(a21, v1, fdot4(a20, v0, 0.f))));
      p3 = fdot4(a33, v3, fdot4(a32, v2, fdot4(a31, v1, fdot4(a30, v0, 0.f))));
    }

    // ---------- phase B: own h(s-1), HOT spin (critical link) ----------
    uint hu = 0;
    if (s > 0) {
      const u64* po = &g_S[st][s - 1][tid];
      for (;;) {
        const u64 b = __hip_atomic_load(po, __ATOMIC_RELAXED, __HIP_MEMORY_SCOPE_AGENT);
        if (b >> 32) { hu = (uint)b; break; }
      }
    }
    *(uint*)&cb[wbh] = hu;
    __syncthreads();   // bar2: H half ready

    // ---------- H-dot: 4 rows x 32 H-cols ----------
    {
      const u32x4 v0 = *(const u32x4*)&cb[rh0];
      const u32x4 v1 = *(const u32x4*)&cb[rh1];
      const u32x4 v2 = *(const u32x4*)&cb[rh2];
      const u32x4 v3 = *(const u32x4*)&cb[rh3];
      p0 = fdot4(b03, v3, fdot4(b02, v2, fdot4(b01, v1, fdot4(b00, v0, p0))));
      p1 = fdot4(b13, v3, fdot4(b12, v2, fdot4(b11, v1, fdot4(b10, v0, p1))));
      p2 = fdot4(b23, v3, fdot4(b22, v2, fdot4(b21, v1, fdot4(b20, v0, p2))));
      p3 = fdot4(b33, v3, fdot4(b32, v2, fdot4(b31, v1, fdot4(b30, v0, p3))));
    }

    // ---------- reduce over c (32-lane group) via DPP: results in lanes 31/63 ----------
    p0 = dpp_reduce32(p0);
    p1 = dpp_reduce32(p1);
    p2 = dpp_reduce32(p2);
    p3 = dpp_reduce32(p3);
    if (isPub) {
      const float h0 = tanhf(p0 + ba.x);
      const float h1 = tanhf(p1 + ba.y);
      const float h2 = tanhf(p2 + ba.z);
      const float h3 = tanhf(p3 + ba.w);
      u64* sp = &g_S[st][s][slot0];
      __hip_atomic_store(&sp[0], (1ull << 32) | (u64)pk2(h0, h1),
                         __ATOMIC_RELAXED, __HIP_MEMORY_SCOPE_AGENT);
      __hip_atomic_store(&sp[1], (1ull << 32) | (u64)pk2(h2, h3),
                         __ATOMIC_RELAXED, __HIP_MEMORY_SCOPE_AGENT);
      if (st & 1)
        *(float4*)&g_Hout[st >> 1][(size_t)s * NN + row0] =
            make_float4(h0, h1, h2, h3);
    }
    // no trailing barrier: tick s+1 writes comb[(s+1)&1]; X/H halves of comb[s&1]
    // are next written at tick s+2, separated by bar1/bar2 of tick s+1.
  }
}

extern "C" void kernel_launch(void* const* d_in, const int* in_sizes, int n_in,
                              void* d_out, int out_size, void* d_ws, size_t ws_size,
                              hipStream_t stream) {
  (void)in_sizes; (void)n_in; (void)out_size; (void)d_ws; (void)ws_size;
  const float* x    = (const float*)d_in[0];
  const float* Wih  = (const float*)d_in[1];
  const float* Whh  = (const float*)d_in[2];
  const float* bih  = (const float*)d_in[3];
  const float* bhh  = (const float*)d_in[4];
  const float* linW = (const float*)d_in[5];
  const float* linb = (const float*)d_in[6];
  float* out = (float*)d_out;

  k_init<<<2048, 256, 0, stream>>>();
  k_pack<<<2048, 256, 0, stream>>>(Wih, Whh, linW);
  k_fold<<<dim3(8, 8, 7), 256, 0, stream>>>(0);
  k_bias<<<dim3(16, 4), 256, 0, stream>>>(Wih, bih, bhh, linb);
  k_phase<<<256, 512, 0, stream>>>(x);
  k_out<<<dim3(8, 8, 8), 256, 0, stream>>>(linb, out);
}

// Round 17
// 1914.823 us; speedup vs baseline: 1.3914x; 1.3914x over previous
//
#include <hip/hip_runtime.h>
#include <hip/hip_fp16.h>

#define NN 1024
#define NST 16

typedef _Float16 v2h __attribute__((ext_vector_type(2)));
typedef _Float16 f16x8 __attribute__((ext_vector_type(8)));
typedef float f32x4 __attribute__((ext_vector_type(4)));
typedef unsigned int uint;
typedef unsigned long long u64;
typedef unsigned int u32x4 __attribute__((ext_vector_type(4)));

// Static device scratch.
__device__ __half g_W[NST][NN][2048];      // per stage row: [Wih_eff(1024) | Whh(1024)] fp16
__device__ float g_bias[NST][NN];          // combined bias fp32
__device__ u64 g_S[NST][NN][512];          // slot q = {1<<32 | fp16 h[2q+1],h[2q]}
__device__ float g_Hout[8][NN * NN];       // h of odd stages (pre-linear), fp32
__device__ _Float16 g_Wih16F[7][NN * NN];  // f16 Wih of folded stages (st=2t, t=1..7)
__device__ _Float16 g_linW16[8][NN * NN];  // f16 linW

__device__ __forceinline__ v2h as_v2h(uint u) {
  union { uint u; v2h h; } c; c.u = u; return c.h;
}
__device__ __forceinline__ uint pk2(float a, float b) {
  union { v2h h; uint u; } c; c.h.x = (_Float16)a; c.h.y = (_Float16)b; return c.u;
}
// 16B-unit swizzle: low3' = (u + (u>>3)) & 7 (R12-proven pattern).
__device__ __forceinline__ int swzu(int u) {
  return (u & ~7) | ((u + (u >> 3)) & 7);
}
// Opaque (non-rematerializable) 16B load.
__device__ __forceinline__ u32x4 ld_opaque16(const __half* p) {
  u32x4 r;
  asm volatile("global_load_dwordx4 %0, %1, off" : "=v"(r) : "v"(p));
  return r;
}
__device__ __forceinline__ float fdot4(u32x4 w, u32x4 v, float a) {
  a = __builtin_amdgcn_fdot2(as_v2h(w.x), as_v2h(v.x), a, false);
  a = __builtin_amdgcn_fdot2(as_v2h(w.y), as_v2h(v.y), a, false);
  a = __builtin_amdgcn_fdot2(as_v2h(w.z), as_v2h(v.z), a, false);
  a = __builtin_amdgcn_fdot2(as_v2h(w.w), as_v2h(v.w), a, false);
  return a;
}
// 16-lane-group sum via DPP row_shr; full sum lands in lane 15 of each group.
__device__ __forceinline__ float dpp_reduce16(float v) {
  int t;
  t = __builtin_amdgcn_update_dpp(0, __float_as_int(v), 0x111, 0xF, 0xF, true); v += __int_as_float(t);
  t = __builtin_amdgcn_update_dpp(0, __float_as_int(v), 0x112, 0xF, 0xF, true); v += __int_as_float(t);
  t = __builtin_amdgcn_update_dpp(0, __float_as_int(v), 0x114, 0xF, 0xF, true); v += __int_as_float(t);
  t = __builtin_amdgcn_update_dpp(0, __float_as_int(v), 0x118, 0xF, 0xF, true); v += __int_as_float(t);
  return v;
}
// Fast tanh via HW exp2/rcp: 1 - 2/(e^{2x}+1). Saturates correctly; rel err ~1e-6.
__device__ __forceinline__ float fast_tanh(float x) {
  const float e = __builtin_amdgcn_exp2f(x * 2.8853900817779268f);  // e^{2x}
  return 1.0f - 2.0f * __builtin_amdgcn_rcpf(e + 1.0f);
}

// ---- zero exchange slots (every launch, replay determinism) ----
__global__ void k_init() {
  const size_t n = (size_t)NST * NN * 512;
  size_t i = (size_t)blockIdx.x * blockDim.x + threadIdx.x;
  const size_t stride = (size_t)gridDim.x * blockDim.x;
  u64* p = &g_S[0][0][0];
  for (; i < n; i += stride) p[i] = 0ull;
}

// ---- pack to fp16: g_W (Whh all, Wih non-folded), g_Wih16F (folded), g_linW16 ----
__global__ void k_pack(const float* __restrict__ Wih, const float* __restrict__ Whh,
                       const float* __restrict__ linW) {
  const size_t total = (size_t)NST * NN * NN;
  const size_t stride = (size_t)gridDim.x * blockDim.x;
  for (size_t i = (size_t)blockIdx.x * blockDim.x + threadIdx.x; i < total; i += stride) {
    const int st = (int)(i >> 20);
    const int m = (int)(i >> 10) & 1023;
    const int k = (int)i & 1023;
    g_W[st][m][1024 + k] = __float2half(Whh[i]);
    const int t = st >> 1, l = st & 1;
    if (l == 1 || t == 0) g_W[st][m][k] = __float2half(Wih[i]);
    else g_Wih16F[t - 1][(size_t)m * NN + k] = (_Float16)Wih[i];
  }
  const size_t ltotal = (size_t)8 * NN * NN;
  _Float16* lw = &g_linW16[0][0];
  for (size_t i = (size_t)blockIdx.x * blockDim.x + threadIdx.x; i < ltotal; i += stride)
    lw[i] = (_Float16)linW[i];
}

#define GPAD 40   // LDS f16 row stride for 32-wide K tiles

// ---- MFMA fold: W'(st=2t) = Wih16F[t-1] @ linW16[t-1], f32 accum -> f16 into g_W ----
__global__ __launch_bounds__(256) void k_fold(int dummy) {
  const int tm1 = blockIdx.z;
  const int st = (tm1 + 1) * 2;
  const _Float16* A = &g_Wih16F[tm1][0];
  const _Float16* B = &g_linW16[tm1][0];
  __shared__ _Float16 sA[128 * GPAD];
  __shared__ _Float16 sB[128 * GPAD];
  const int tid = threadIdx.x;
  const int bm = blockIdx.y << 7, bn = blockIdx.x << 7;
  const int lane = tid & 63, wid = tid >> 6;
  const int wm = wid >> 1, wn = wid & 1;
  const int lr = lane & 15, kc = (lane >> 4) << 3;
  f32x4 acc[4][4] = {};
  const int arow = tid >> 1, ahalf = tid & 1;           // A/B row staging
  const int bj = tid >> 3, bcs = tid & 7;               // B transpose staging

  for (int k0 = 0; k0 < NN; k0 += 32) {
    __syncthreads();
    {
      const u32x4 a0 = *(const u32x4*)&A[(size_t)(bm + arow) * NN + k0 + 16 * ahalf];
      const u32x4 a1 = *(const u32x4*)&A[(size_t)(bm + arow) * NN + k0 + 16 * ahalf + 8];
      u32x4* dst = (u32x4*)&sA[arow * GPAD + 16 * ahalf];
      dst[0] = a0; dst[1] = a1;
      union { u32x4 v; _Float16 h[8]; } ua, ub;
      ua.v = *(const u32x4*)&B[(size_t)(k0 + bj) * NN + bn + 16 * bcs];
      ub.v = *(const u32x4*)&B[(size_t)(k0 + bj) * NN + bn + 16 * bcs + 8];
      #pragma unroll
      for (int q = 0; q < 8; ++q) sB[(16 * bcs + q) * GPAD + bj] = ua.h[q];
      #pragma unroll
      for (int q = 0; q < 8; ++q) sB[(16 * bcs + 8 + q) * GPAD + bj] = ub.h[q];
    }
    __syncthreads();
    f16x8 af[4], bf[4];
    #pragma unroll
    for (int f = 0; f < 4; ++f) {
      af[f] = *(const f16x8*)&sA[(wm * 64 + f * 16 + lr) * GPAD + kc];
      bf[f] = *(const f16x8*)&sB[(wn * 64 + f * 16 + lr) * GPAD + kc];
    }
    #pragma unroll
    for (int fm = 0; fm < 4; ++fm)
      #pragma unroll
      for (int fn = 0; fn < 4; ++fn)
        acc[fm][fn] = __builtin_amdgcn_mfma_f32_16x16x32_f16(af[fm], bf[fn], acc[fm][fn], 0, 0, 0);
  }
  const int orow = (lane >> 4) << 2, ocol = lane & 15;
  #pragma unroll
  for (int fm = 0; fm < 4; ++fm)
    #pragma unroll
    for (int fn = 0; fn < 4; ++fn) {
      const int gr = bm + wm * 64 + fm * 16 + orow;
      const int gc = bn + wn * 64 + fn * 16 + ocol;
      #pragma unroll
      for (int r = 0; r < 4; ++r)
        g_W[st][gr + r][gc] = __float2half(acc[fm][fn][r]);
    }
}

// ---- MFMA epilogue: out[s][t][n] = Hout[t][s] @ linW16[t]^T + linb[t] ----
__global__ __launch_bounds__(256) void k_out(const float* __restrict__ linb,
                                             float* __restrict__ out) {
  const int t = blockIdx.z;
  const float* A = &g_Hout[t][0];
  const _Float16* B = &g_linW16[t][0];
  __shared__ _Float16 sA[128 * GPAD];
  __shared__ _Float16 sB[128 * GPAD];
  const int tid = threadIdx.x;
  const int bm = blockIdx.y << 7, bn = blockIdx.x << 7;
  const int lane = tid & 63, wid = tid >> 6;
  const int wm = wid >> 1, wn = wid & 1;
  const int lr = lane & 15, kc = (lane >> 4) << 3;
  f32x4 acc[4][4] = {};
  const int arow = tid >> 1, ahalf = tid & 1;

  for (int k0 = 0; k0 < NN; k0 += 32) {
    __syncthreads();
    {
      const float* srcA = &A[(size_t)(bm + arow) * NN + k0 + 16 * ahalf];
      const float4 f0 = *(const float4*)&srcA[0];
      const float4 f1 = *(const float4*)&srcA[4];
      const float4 f2 = *(const float4*)&srcA[8];
      const float4 f3 = *(const float4*)&srcA[12];
      u32x4 o0, o1;
      o0.x = pk2(f0.x, f0.y); o0.y = pk2(f0.z, f0.w);
      o0.z = pk2(f1.x, f1.y); o0.w = pk2(f1.z, f1.w);
      o1.x = pk2(f2.x, f2.y); o1.y = pk2(f2.z, f2.w);
      o1.z = pk2(f3.x, f3.y); o1.w = pk2(f3.z, f3.w);
      u32x4* dstA = (u32x4*)&sA[arow * GPAD + 16 * ahalf];
      dstA[0] = o0; dstA[1] = o1;
      const u32x4 b0 = *(const u32x4*)&B[(size_t)(bn + arow) * NN + k0 + 16 * ahalf];
      const u32x4 b1 = *(const u32x4*)&B[(size_t)(bn + arow) * NN + k0 + 16 * ahalf + 8];
      u32x4* dstB = (u32x4*)&sB[arow * GPAD + 16 * ahalf];
      dstB[0] = b0; dstB[1] = b1;
    }
    __syncthreads();
    f16x8 af[4], bf[4];
    #pragma unroll
    for (int f = 0; f < 4; ++f) {
      af[f] = *(const f16x8*)&sA[(wm * 64 + f * 16 + lr) * GPAD + kc];
      bf[f] = *(const f16x8*)&sB[(wn * 64 + f * 16 + lr) * GPAD + kc];
    }
    #pragma unroll
    for (int fm = 0; fm < 4; ++fm)
      #pragma unroll
      for (int fn = 0; fn < 4; ++fn)
        acc[fm][fn] = __builtin_amdgcn_mfma_f32_16x16x32_f16(af[fm], bf[fn], acc[fm][fn], 0, 0, 0);
  }
  const int orow = (lane >> 4) << 2, ocol = lane & 15;
  #pragma unroll
  for (int fm = 0; fm < 4; ++fm)
    #pragma unroll
    for (int fn = 0; fn < 4; ++fn) {
      const int gr = bm + wm * 64 + fm * 16 + orow;
      const int gc = bn + wn * 64 + fn * 16 + ocol;
      const float lb = linb[(size_t)t * NN + gc];
      #pragma unroll
      for (int r = 0; r < 4; ++r)
        out[(size_t)(gr + r) * 8192 + (size_t)t * NN + gc] = acc[fm][fn][r] + lb;
    }
}

// ---- combined bias per stage (64 WGs) ----
__global__ __launch_bounds__(256) void k_bias(const float* __restrict__ Wih,
    const float* __restrict__ bih, const float* __restrict__ bhh,
    const float* __restrict__ linb) {
  const int st = blockIdx.x, t = st >> 1, l = st & 1;
  const int tid = threadIdx.x;
  const int m = (blockIdx.y << 8) + tid;
  __shared__ float slb[NN];
  const bool folded = (l == 0 && t > 0);
  if (folded)
    for (int k = tid; k < NN; k += 256) slb[k] = linb[(size_t)(t - 1) * NN + k];
  __syncthreads();
  float b = bih[(size_t)st * NN + m] + bhh[(size_t)st * NN + m];
  if (folded) {
    const float* wr = Wih + (size_t)st * NN * NN + (size_t)m * NN;
    float s0 = 0, s1 = 0, s2 = 0, s3 = 0;
    for (int k = 0; k < NN; k += 4) {
      const float4 w = *(const float4*)&wr[k];
      s0 += w.x * slb[k]; s1 += w.y * slb[k + 1];
      s2 += w.z * slb[k + 2]; s3 += w.w * slb[k + 3];
    }
    b += (s0 + s1) + (s2 + s3);
  }
  g_bias[st][m] = b;
}

// ---- pipelined 16-stage scan (R14-proven core): 256 WGs x 512 thr, 1 WG/CU ----
// Thread (i=tid>>4, c=tid&15): rows woff+2i..+1, cols [64c,64c+64) of X AND H.
// Split-phase tick; DPP reduce (lane 15 publishes); fast tanh on publish tail.
__global__ __launch_bounds__(512)
__attribute__((amdgpu_waves_per_eu(2, 2)))
void k_phase(const float* __restrict__ x) {
  __shared__ __align__(16) unsigned char comb[2][4096];
  const int tid = threadIdx.x;
  const int bid = blockIdx.x;
  const int st = ((bid & 7) << 1) + (bid >> 7);
  const int wg = (bid >> 3) & 15;
  const int woff = wg << 6;
  const int i = tid >> 4;
  const int c = tid & 15;

#define LDX(RR, JJ) ld_opaque16(&g_W[st][woff + 2 * i + (RR)][64 * c + 8 * (JJ)])
#define LDH(RR, JJ) ld_opaque16(&g_W[st][woff + 2 * i + (RR)][1024 + 64 * c + 8 * (JJ)])
  u32x4 x00 = LDX(0,0), x01 = LDX(0,1), x02 = LDX(0,2), x03 = LDX(0,3);
  u32x4 x04 = LDX(0,4), x05 = LDX(0,5), x06 = LDX(0,6), x07 = LDX(0,7);
  u32x4 x10 = LDX(1,0), x11 = LDX(1,1), x12 = LDX(1,2), x13 = LDX(1,3);
  u32x4 x14 = LDX(1,4), x15 = LDX(1,5), x16 = LDX(1,6), x17 = LDX(1,7);
  u32x4 h00 = LDH(0,0), h01 = LDH(0,1), h02 = LDH(0,2), h03 = LDH(0,3);
  u32x4 h04 = LDH(0,4), h05 = LDH(0,5), h06 = LDH(0,6), h07 = LDH(0,7);
  u32x4 h10 = LDH(1,0), h11 = LDH(1,1), h12 = LDH(1,2), h13 = LDH(1,3);
  u32x4 h14 = LDH(1,4), h15 = LDH(1,5), h16 = LDH(1,6), h17 = LDH(1,7);
#undef LDX
#undef LDH
  asm volatile("s_waitcnt vmcnt(0)" ::: "memory");
  __builtin_amdgcn_sched_barrier(0);

  const float2 breg = *(const float2*)&g_bias[st][woff + 2 * i];

  const int uW = tid >> 2, off4 = (tid & 3) << 2;
  const int wbx = swzu(uW) * 16 + off4;
  const int wbh = swzu(128 + uW) * 16 + off4;
  const int slot_pub = (woff >> 1) + i;

  for (int s = 0; s < NN; ++s) {
    unsigned char* cb = comb[s & 1];
    uint xu = 0;
    if (st == 0) {
      const float2 xv = *(const float2*)&x[(size_t)s * 8192 + 2 * tid];
      xu = pk2(xv.x, xv.y);
    } else {
      const u64* pu = &g_S[st - 1][s][tid];
      for (;;) {
        const u64 a = __hip_atomic_load(pu, __ATOMIC_RELAXED, __HIP_MEMORY_SCOPE_AGENT);
        if (a >> 32) { xu = (uint)a; break; }
        __builtin_amdgcn_s_sleep(1);
      }
    }
    *(uint*)&cb[wbx] = xu;
    __syncthreads();

    float p0 = 0.f, p1 = 0.f;
#define XSTEP(JJ, Q0, Q1) { \
      const u32x4 v = *(const u32x4*)&cb[swzu(8 * c + (JJ)) * 16]; \
      p0 = fdot4(Q0, v, p0); p1 = fdot4(Q1, v, p1); }
    XSTEP(0, x00, x10) XSTEP(1, x01, x11) XSTEP(2, x02, x12) XSTEP(3, x03, x13)
    XSTEP(4, x04, x14) XSTEP(5, x05, x15) XSTEP(6, x06, x16) XSTEP(7, x07, x17)
#undef XSTEP

    uint hu = 0;
    if (s > 0) {
      const u64* po = &g_S[st][s - 1][tid];
      for (;;) {
        const u64 b = __hip_atomic_load(po, __ATOMIC_RELAXED, __HIP_MEMORY_SCOPE_AGENT);
        if (b >> 32) { hu = (uint)b; break; }
      }
    }
    *(uint*)&cb[wbh] = hu;
    __syncthreads();

#define HSTEP(JJ, Q0, Q1) { \
      const u32x4 v = *(const u32x4*)&cb[swzu(128 + 8 * c + (JJ)) * 16]; \
      p0 = fdot4(Q0, v, p0); p1 = fdot4(Q1, v, p1); }
    HSTEP(0, h00, h10) HSTEP(1, h01, h11) HSTEP(2, h02, h12) HSTEP(3, h03, h13)
    HSTEP(4, h04, h14) HSTEP(5, h05, h15) HSTEP(6, h06, h16) HSTEP(7, h07, h17)
#undef HSTEP

    p0 = dpp_reduce16(p0);
    p1 = dpp_reduce16(p1);
    if (c == 15) {
      const float hv0 = fast_tanh(p0 + breg.x);
      const float hv1 = fast_tanh(p1 + breg.y);
      const u64 pv = (1ull << 32) | (u64)pk2(hv0, hv1);
      __hip_atomic_store(&g_S[st][s][slot_pub], pv,
                         __ATOMIC_RELAXED, __HIP_MEMORY_SCOPE_AGENT);
      if (st & 1)
        *(float2*)&g_Hout[st >> 1][(size_t)s * NN + woff + 2 * i] =
            make_float2(hv0, hv1);
    }
  }
}

extern "C" void kernel_launch(void* const* d_in, const int* in_sizes, int n_in,
                              void* d_out, int out_size, void* d_ws, size_t ws_size,
                              hipStream_t stream) {
  (void)in_sizes; (void)n_in; (void)out_size; (void)d_ws; (void)ws_size;
  const float* x    = (const float*)d_in[0];
  const float* Wih  = (const float*)d_in[1];
  const float* Whh  = (const float*)d_in[2];
  const float* bih  = (const float*)d_in[3];
  const float* bhh  = (const float*)d_in[4];
  const float* linW = (const float*)d_in[5];
  const float* linb = (const float*)d_in[6];
  float* out = (float*)d_out;

  k_init<<<2048, 256, 0, stream>>>();
  k_pack<<<2048, 256, 0, stream>>>(Wih, Whh, linW);
  k_fold<<<dim3(8, 8, 7), 256, 0, stream>>>(0);
  k_bias<<<dim3(16, 4), 256, 0, stream>>>(Wih, bih, bhh, linb);
  k_phase<<<256, 512, 0, stream>>>(x);
  k_out<<<dim3(8, 8, 8), 256, 0, stream>>>(linb, out);
}